// Round 5
// baseline (530.824 us; speedup 1.0000x reference)
//
#include <hip/hip_runtime.h>
#include <hip/hip_bf16.h>

// BaseQVLayer fused: xp = x@Wx+bx; yp = y@Wy+by;
// At[j,i] = 2*(yp_j.xp_i)/(Dx_i+Dy_j) is NEVER materialized — k_fuse computes
// S-tiles (64x256) in-register, LDS round-trip (C->A layout, XOR-swizzled),
// immediately consumed by gwf-acc += S @ xpT. out = relu(gwf@Wg+bg).
//
// Pipeline: k_cvt(x,y->bf16) -> k_proj x2 -> t_bf16(xpT) -> k_fuse -> k_out.
// Workspace ~91 MB: xb 16 | yb 16 | xpb 8 | ypb 8 | xpT 8 | P0 16 | P1 16 |
//                   WxT 1 | WyT 1 | WgT .5 | Dx,Dy
//
// R4 retry: byte-identical resubmit after broker-side container failure
// (no kernel evidence of fault; audit found no hang/OOB path).

typedef __attribute__((ext_vector_type(8))) short bf16x8;
typedef __attribute__((ext_vector_type(4))) short bf16x4;
typedef __attribute__((ext_vector_type(4))) float f32x4;

__device__ __forceinline__ short f2b(float f) {
    unsigned int u = __builtin_bit_cast(unsigned int, f);
    unsigned int r = (u + 0x7fffu + ((u >> 16) & 1u)) >> 16;
    return (short)r;
}

// async global->LDS, 16 B/lane. LDS dest = wave-uniform base + lane*16.
__device__ __forceinline__ void cp16(const void* g, void* l) {
    __builtin_amdgcn_global_load_lds(
        (const __attribute__((address_space(1))) void*)g,
        (__attribute__((address_space(3))) void*)l, 16, 0, 0);
}

// ============================ k_fuse =======================================
// 256 blocks x 512 threads (8 waves). Block: j-tile 64 (yp rows), iz in {0,1}
// selects i-half; 16 i-tiles of 256. LDS exactly 64 KB.
// P1: S[64x256] = yp_tile @ xp_tile^T, K=512; waves 2(j)x4(i), wave-tile 32x64.
// P2: acc2[64x(64e per wave)] += S @ xpT, K=256; wave-tile 64x64.
// Staging buffers use 2-bit XOR granule swizzle (slot = g ^ (row&3));
// S uses 3-bit swizzle (slot = k8 ^ (row&7)) -> conflict-free A-frag reads.
__global__ __launch_bounds__(512, 2)
void k_fuse(const short* __restrict__ ypb, const short* __restrict__ xpb,
            const short* __restrict__ xpT, const float* __restrict__ Dy,
            const float* __restrict__ Dx,
            float* __restrict__ P0, float* __restrict__ P1)
{
    __shared__ __align__(16) short lds[32768];   // 65536 B exactly
    short* Sl  = lds;          // [64][256] swizzled, 32 KB
    short* As1 = lds + 16384;  // [64][32]  4 KB   (P1)
    short* Bs1 = lds + 18432;  // [256][32] 16 KB  (P1)
    short* Bs2 = lds + 16384;  // [512][32] 32 KB  (P2, aliases As1+Bs1)

    const int tid  = threadIdx.x;
    const int wave = tid >> 6;
    const int lane = tid & 63;
    const int quad = lane >> 4;
    const int l15  = lane & 15;

    const int bid = blockIdx.x;
    const int xcd = bid & 7;
    const int iz  = xcd >> 2;                  // 4 XCDs per i-half
    const int jt  = (xcd & 3) * 32 + (bid >> 3);
    const int jbase = jt * 64;
    const int ibase = iz * 4096;
    float* __restrict__ Pz = iz ? P1 : P0;

    const int wj = wave >> 2;                  // P1: j-half 0..1
    const int wi = wave & 3;                   // P1: i-quarter 0..3

    f32x4 acc2[4][4];
#pragma unroll
    for (int i = 0; i < 4; i++)
#pragma unroll
        for (int j = 0; j < 4; j++) acc2[i][j] = f32x4{0.f, 0.f, 0.f, 0.f};

    for (int it = 0; it < 16; ++it) {
        const int i0 = ibase + it * 256;

        // ---------------- P1: S = scale * (yp @ xp^T) ----------------
        f32x4 acc1[2][4];
#pragma unroll
        for (int i = 0; i < 2; i++)
#pragma unroll
            for (int j = 0; j < 4; j++) acc1[i][j] = f32x4{0.f, 0.f, 0.f, 0.f};

        for (int ks = 0; ks < 16; ++ks) {
            const int kk = ks * 32;
            if (tid < 256) {                       // As1: 64 rows x 4 granules
                const int row = tid >> 2, g = tid & 3;
                const int gg = g ^ (row & 3);      // swizzle: slot g holds granule gg
                cp16(&ypb[(size_t)(jbase + row) * 512 + kk + gg * 8], &As1[tid * 8]);
            }
#pragma unroll
            for (int c = 0; c < 2; ++c) {          // Bs1: 256 rows x 4 granules
                const int s = tid + 512 * c;
                const int row = s >> 2, g = s & 3;
                const int gg = g ^ (row & 3);
                cp16(&xpb[(size_t)(i0 + row) * 512 + kk + gg * 8], &Bs1[s * 8]);
            }
            __syncthreads();

            bf16x8 a[2], b[4];
#pragma unroll
            for (int mf = 0; mf < 2; ++mf) {
                const int row = wj * 32 + mf * 16 + l15;
                a[mf] = *(const bf16x8*)&As1[row * 32 + (quad ^ (row & 3)) * 8];
            }
#pragma unroll
            for (int nf = 0; nf < 4; ++nf) {
                const int row = wi * 64 + nf * 16 + l15;
                b[nf] = *(const bf16x8*)&Bs1[row * 32 + (quad ^ (row & 3)) * 8];
            }
#pragma unroll
            for (int mf = 0; mf < 2; ++mf)
#pragma unroll
                for (int nf = 0; nf < 4; ++nf)
                    acc1[mf][nf] = __builtin_amdgcn_mfma_f32_16x16x32_bf16(
                        a[mf], b[nf], acc1[mf][nf], 0, 0, 0);
            __syncthreads();
        }

        // scale + write S to LDS (C-layout -> swizzled row-major)
#pragma unroll
        for (int mf = 0; mf < 2; ++mf) {
#pragma unroll
            for (int r = 0; r < 4; ++r) {
                const int row = wj * 32 + mf * 16 + quad * 4 + r;   // j-local
                const float dy = Dy[jbase + row];
#pragma unroll
                for (int nf = 0; nf < 4; ++nf) {
                    const int col = wi * 64 + nf * 16 + l15;        // i-local
                    const float v = 2.f * acc1[mf][nf][r] / (Dx[i0 + col] + dy);
                    const int k8 = col >> 3;
                    Sl[row * 256 + ((k8 ^ (row & 7)) << 3) + (col & 7)] = f2b(v);
                }
            }
        }
        __syncthreads();

        // ---------------- P2: acc2 += S @ xpT-slice ----------------
        for (int ks2 = 0; ks2 < 8; ++ks2) {
#pragma unroll
            for (int c = 0; c < 4; ++c) {          // Bs2: 512 e-rows x 4 granules
                const int s = tid + 512 * c;
                const int row = s >> 2, g = s & 3;
                const int gg = g ^ (row & 3);
                cp16(&xpT[(size_t)row * 8192 + i0 + ks2 * 32 + gg * 8], &Bs2[s * 8]);
            }
            __syncthreads();

            bf16x8 a2[4], b2[4];
#pragma unroll
            for (int mf = 0; mf < 4; ++mf) {
                const int row = mf * 16 + l15;               // j-local
                const int k8 = ks2 * 4 + quad;               // i-granule
                a2[mf] = *(const bf16x8*)&Sl[row * 256 + ((k8 ^ (row & 7)) << 3)];
            }
#pragma unroll
            for (int nf = 0; nf < 4; ++nf) {
                const int row = wave * 64 + nf * 16 + l15;   // e-row
                b2[nf] = *(const bf16x8*)&Bs2[row * 32 + (quad ^ (row & 3)) * 8];
            }
#pragma unroll
            for (int mf = 0; mf < 4; ++mf)
#pragma unroll
                for (int nf = 0; nf < 4; ++nf)
                    acc2[mf][nf] = __builtin_amdgcn_mfma_f32_16x16x32_bf16(
                        a2[mf], b2[nf], acc2[mf][nf], 0, 0, 0);
            __syncthreads();
        }
    }

    // epilogue: f32 partial gwf
#pragma unroll
    for (int mf = 0; mf < 4; ++mf) {
#pragma unroll
        for (int r = 0; r < 4; ++r) {
            const int gj = jbase + mf * 16 + quad * 4 + r;
#pragma unroll
            for (int nf = 0; nf < 4; ++nf) {
                const int ge = wave * 64 + nf * 16 + l15;
                Pz[(size_t)gj * 512 + ge] = acc2[mf][nf][r];
            }
        }
    }
}

// ==================== small-GEMM core (k_proj, k_out) ======================
constexpr int EPI_XP  = 0;   // +bias, store bf16, atomic row-norm accumulate
constexpr int EPI_OUT = 1;   // +bias, relu, store f32
constexpr int ASRC_BF16    = 0;
constexpr int ASRC_F32SUM2 = 1;   // A = P0 + P1 (f32), converted during staging

template<int EPI, int ASRC>
__global__ __launch_bounds__(256)
void gemm64(const void* __restrict__ Aptr, const void* __restrict__ Aptr2, int lda,
            const short* __restrict__ Bt, int ldb, int N, int K,
            const float* __restrict__ bias,
            short* __restrict__ outb, float* __restrict__ outf,
            float* __restrict__ Dacc)
{
    __shared__ __align__(16) short As[64 * 32];
    __shared__ __align__(16) short Bs[128 * 32];

    const int tid  = threadIdx.x;
    const int wave = tid >> 6;
    const int lane = tid & 63;
    const int quad = lane >> 4;
    const int l15  = lane & 15;
    const int wm   = (wave >> 1) * 32;
    const int wn   = (wave & 1) * 64;
    const int bm   = blockIdx.y * 64;
    const int bn   = blockIdx.x * 128;

    f32x4 acc[2][4];
#pragma unroll
    for (int i = 0; i < 2; i++)
#pragma unroll
        for (int j = 0; j < 4; j++) acc[i][j] = f32x4{0.f, 0.f, 0.f, 0.f};

    for (int k0 = 0; k0 < K; k0 += 32) {
        if (ASRC == ASRC_BF16) {
            const short* Ab = (const short*)Aptr;
            const int row = tid >> 2, c8 = tid & 3;        // 256 segs
            cp16(&Ab[(size_t)(bm + row) * lda + k0 + c8 * 8], &As[tid * 8]);
        } else {
            const float* A0 = (const float*)Aptr;
            const float* A1 = (const float*)Aptr2;
#pragma unroll
            for (int c = 0; c < 2; ++c) {                  // 512 f32x4 segs
                const int s = tid + 256 * c;
                const int row = s >> 3, g4 = s & 7;
                const size_t off = (size_t)(bm + row) * lda + k0 + g4 * 4;
                const float4 v0 = *(const float4*)&A0[off];
                const float4 v1 = *(const float4*)&A1[off];
                bf16x4 b;
                b[0] = f2b(v0.x + v1.x); b[1] = f2b(v0.y + v1.y);
                b[2] = f2b(v0.z + v1.z); b[3] = f2b(v0.w + v1.w);
                *(bf16x4*)&As[row * 32 + g4 * 4] = b;
            }
        }
#pragma unroll
        for (int c = 0; c < 2; ++c) {                      // Bs: 128 rows x 4
            const int s = tid + 256 * c;
            const int row = s >> 2, c8 = s & 3;
            cp16(&Bt[(size_t)(bn + row) * ldb + k0 + c8 * 8], &Bs[s * 8]);
        }
        __syncthreads();

        bf16x8 af[2], bfr[4];
#pragma unroll
        for (int i = 0; i < 2; i++)
            af[i] = *(const bf16x8*)&As[(wm + i * 16 + l15) * 32 + quad * 8];
#pragma unroll
        for (int j = 0; j < 4; j++)
            bfr[j] = *(const bf16x8*)&Bs[(wn + j * 16 + l15) * 32 + quad * 8];
#pragma unroll
        for (int i = 0; i < 2; i++)
#pragma unroll
            for (int j = 0; j < 4; j++)
                acc[i][j] = __builtin_amdgcn_mfma_f32_16x16x32_bf16(af[i], bfr[j], acc[i][j], 0, 0, 0);
        __syncthreads();
    }

#pragma unroll
    for (int im = 0; im < 2; ++im) {
#pragma unroll
        for (int r = 0; r < 4; ++r) {
            const int gm = bm + wm + im * 16 + quad * 4 + r;
            if (EPI == EPI_XP) {
                float s = 0.f;
#pragma unroll
                for (int jn = 0; jn < 4; ++jn) {
                    const int gn = bn + wn + jn * 16 + l15;
                    const float v = acc[im][jn][r] + bias[gn];
                    outb[(size_t)gm * N + gn] = f2b(v);
                    s += v * v;
                }
#pragma unroll
                for (int m = 1; m < 16; m <<= 1) s += __shfl_xor(s, m, 64);
                if (l15 == 0) atomicAdd(&Dacc[gm], s);
            } else {
#pragma unroll
                for (int jn = 0; jn < 4; ++jn) {
                    const int gn = bn + wn + jn * 16 + l15;
                    const float v = acc[im][jn][r] + bias[gn];
                    outf[(size_t)gm * N + gn] = fmaxf(v, 0.f);
                }
            }
        }
    }
}

// =========================== helpers =======================================
__global__ __launch_bounds__(256)
void k_cvt(const float* __restrict__ in, short* __restrict__ out)
{
    const int i = (blockIdx.x * 256 + threadIdx.x) * 4;
    const float4 v = *(const float4*)&in[i];
    bf16x4 b;
    b[0] = f2b(v.x); b[1] = f2b(v.y); b[2] = f2b(v.z); b[3] = f2b(v.w);
    *(bf16x4*)&out[i] = b;
}

__global__ __launch_bounds__(256)
void transpose_f32_bf16(const float* __restrict__ in, short* __restrict__ out, int R, int C)
{
    __shared__ short t[32][33];
    const int tx = threadIdx.x, ty = threadIdx.y;
    const int bx = blockIdx.x * 32, by = blockIdx.y * 32;
#pragma unroll
    for (int i = 0; i < 32; i += 8)
        t[ty + i][tx] = f2b(in[(size_t)(by + ty + i) * C + bx + tx]);
    __syncthreads();
#pragma unroll
    for (int i = 0; i < 32; i += 8)
        out[(size_t)(bx + ty + i) * R + by + tx] = t[tx][ty + i];
}

__global__ __launch_bounds__(256)
void transpose_bf16(const short* __restrict__ in, short* __restrict__ out, int R, int C)
{
    __shared__ short t[32][33];
    const int tx = threadIdx.x, ty = threadIdx.y;
    const int bx = blockIdx.x * 32, by = blockIdx.y * 32;
#pragma unroll
    for (int i = 0; i < 32; i += 8)
        t[ty + i][tx] = in[(size_t)(by + ty + i) * C + bx + tx];
    __syncthreads();
#pragma unroll
    for (int i = 0; i < 32; i += 8)
        out[(size_t)(bx + ty + i) * R + by + tx] = t[tx][ty + i];
}

extern "C" void kernel_launch(void* const* d_in, const int* in_sizes, int n_in,
                              void* d_out, int out_size, void* d_ws, size_t ws_size,
                              hipStream_t stream)
{
    const float* x  = (const float*)d_in[0];
    const float* y  = (const float*)d_in[1];
    const float* Wx = (const float*)d_in[2];
    const float* bx = (const float*)d_in[3];
    const float* Wy = (const float*)d_in[4];
    const float* by = (const float*)d_in[5];
    const float* Wg = (const float*)d_in[6];
    const float* bg = (const float*)d_in[7];
    float* out = (float*)d_out;                // [8192, 512] f32

    char* p = (char*)d_ws;
    short* xb   = (short*)p; p += (size_t)8192 * 1024 * 2;
    short* yb   = (short*)p; p += (size_t)8192 * 1024 * 2;
    short* xpb  = (short*)p; p += (size_t)8192 * 512 * 2;
    short* ypb  = (short*)p; p += (size_t)8192 * 512 * 2;
    short* xpT  = (short*)p; p += (size_t)512 * 8192 * 2;
    float* P0   = (float*)p; p += (size_t)8192 * 512 * 4;
    float* P1   = (float*)p; p += (size_t)8192 * 512 * 4;
    short* WxT  = (short*)p; p += (size_t)512 * 1024 * 2;
    short* WyT  = (short*)p; p += (size_t)512 * 1024 * 2;
    short* WgT  = (short*)p; p += (size_t)512 * 512 * 2;
    float* Dx   = (float*)p; p += (size_t)8192 * 4;
    float* Dy   = (float*)p; p += (size_t)8192 * 4;

    hipMemsetAsync(Dx, 0, 2 * 8192 * sizeof(float), stream);  // Dx,Dy contiguous

    dim3 tb(32, 8);
    transpose_f32_bf16<<<dim3(512 / 32, 1024 / 32), tb, 0, stream>>>(Wx, WxT, 1024, 512);
    transpose_f32_bf16<<<dim3(512 / 32, 1024 / 32), tb, 0, stream>>>(Wy, WyT, 1024, 512);
    transpose_f32_bf16<<<dim3(512 / 32, 512 / 32),  tb, 0, stream>>>(Wg, WgT, 512, 512);

    k_cvt<<<8192, 256, 0, stream>>>(x, xb);
    k_cvt<<<8192, 256, 0, stream>>>(y, yb);

    // xp = x@Wx + bx (+Dx row norms); yp likewise
    gemm64<EPI_XP, ASRC_BF16><<<dim3(4, 128), 256, 0, stream>>>(
        xb, nullptr, 1024, WxT, 1024, 512, 1024, bx, xpb, nullptr, Dx);
    gemm64<EPI_XP, ASRC_BF16><<<dim3(4, 128), 256, 0, stream>>>(
        yb, nullptr, 1024, WyT, 1024, 512, 1024, by, ypb, nullptr, Dy);

    transpose_bf16<<<dim3(512 / 32, 8192 / 32), tb, 0, stream>>>(xpb, xpT, 8192, 512);

    // fused affinity + aggregation (no At materialization)
    k_fuse<<<256, 512, 0, stream>>>(ypb, xpb, xpT, Dy, Dx, P0, P1);

    // out = relu((P0+P1)@Wg + bg)
    gemm64<EPI_OUT, ASRC_F32SUM2><<<dim3(4, 128), 256, 0, stream>>>(
        P0, P1, 512, WgT, 512, 512, 512, bg, nullptr, out, nullptr);
}

// Round 8
// 396.419 us; speedup vs baseline: 1.3390x; 1.3390x over previous
//
#include <hip/hip_runtime.h>
#include <hip/hip_bf16.h>

// BaseQVLayer, R7 (conservative hybrid — disambiguate infra vs kernel):
//   xp = x@Wx+bx; yp = y@Wy+by    (k_proj + row-norms)
//   zT = Wg^T @ xp^T [512 x 8192] (k_zT; associativity: out = A^T@(xp@Wg)+bg)
//   At[j,i] = 2*(yp_j.xp_i)/(Dx_i+Dy_j)   (k_aff, 128 MB bf16)
//   out = relu(At @ z + bg)               (k_agg -> d_out directly)
//
// Core = R3's device-proven BK=32 cp16 gemm (unpadded stride-32 LDS, scalar
// epilogues). R6's unproven micro-features (BK=64, XOR swizzle, LDS-bounce
// epilogue) deliberately removed to isolate the repeated container failure.
//
// Workspace 154.6 MB: At [0,128 MB) with xb/yb aliased inside (dead after
// k_proj); then xpb 8 | ypb 8 | zT 8 | WxT 1 | WyT 1 | WgT .5 | Dx,Dy.

typedef __attribute__((ext_vector_type(8))) short bf16x8;
typedef __attribute__((ext_vector_type(4))) short bf16x4;
typedef __attribute__((ext_vector_type(4))) float f32x4;

__device__ __forceinline__ short f2b(float f) {
    unsigned int u = __builtin_bit_cast(unsigned int, f);
    unsigned int r = (u + 0x7fffu + ((u >> 16) & 1u)) >> 16;
    return (short)r;
}

// async global->LDS, 16 B/lane. LDS dest = wave-uniform base + lane*16.
__device__ __forceinline__ void cp16(const void* g, void* l) {
    __builtin_amdgcn_global_load_lds(
        (const __attribute__((address_space(1))) void*)g,
        (__attribute__((address_space(3))) void*)l, 16, 0, 0);
}

constexpr int EPI_XP   = 0;  // +bias, store bf16, atomic row-norm
constexpr int EPI_BF   = 1;  // store bf16 (zT)
constexpr int EPI_AT   = 2;  // dice scale, store bf16
constexpr int EPI_RELU = 3;  // +bias, relu, store f32

// C = A @ Bt^T. TM x TN tile, 256 threads (4 waves), BK=32 (R3-proven shape).
// TN=128: waves 2x2, wave-tile (FRM*16)x64. TN=64: waves 4x1, wave-tile 32x64.
template<int EPI, int TM, int TN>
__device__ __forceinline__ void gemm_core(
    const short* __restrict__ A, int lda,
    const short* __restrict__ Bt, int ldb,
    int N, int K, int bm, int bn,
    const float* __restrict__ bias,
    short* __restrict__ outb, float* __restrict__ outf,
    float* __restrict__ Dacc,
    const float* __restrict__ Drow, const float* __restrict__ Dcol)
{
    constexpr int FRM = (TN == 128) ? (TM / 32) : 2;
    __shared__ __align__(16) short As[TM * 32];
    __shared__ __align__(16) short Bs[TN * 32];

    const int tid  = threadIdx.x;
    const int wave = tid >> 6;
    const int lane = tid & 63;
    const int quad = lane >> 4;
    const int l15  = lane & 15;
    const int wn   = (TN == 128) ? (wave & 1) * 64 : 0;
    const int wm   = (TN == 128) ? (wave >> 1) * (FRM * 16) : wave * 32;

    f32x4 acc[FRM][4];
#pragma unroll
    for (int i = 0; i < FRM; i++)
#pragma unroll
        for (int j = 0; j < 4; j++) acc[i][j] = f32x4{0.f, 0.f, 0.f, 0.f};

    for (int k0 = 0; k0 < K; k0 += 32) {
#pragma unroll
        for (int s = 0; s < TM / 64; s++) {          // A: TM rows x 4 granules
            const int seg = tid + 256 * s;
            const int row = seg >> 2, c8 = seg & 3;
            cp16(&A[(size_t)(bm + row) * lda + k0 + c8 * 8], &As[seg * 8]);
        }
#pragma unroll
        for (int s = 0; s < TN / 64; s++) {          // B: TN rows x 4 granules
            const int seg = tid + 256 * s;
            const int row = seg >> 2, c8 = seg & 3;
            cp16(&Bt[(size_t)(bn + row) * ldb + k0 + c8 * 8], &Bs[seg * 8]);
        }
        __syncthreads();

        bf16x8 a[FRM], b[4];
#pragma unroll
        for (int i = 0; i < FRM; i++)
            a[i] = *(const bf16x8*)&As[(wm + i * 16 + l15) * 32 + quad * 8];
#pragma unroll
        for (int j = 0; j < 4; j++)
            b[j] = *(const bf16x8*)&Bs[(wn + j * 16 + l15) * 32 + quad * 8];
#pragma unroll
        for (int i = 0; i < FRM; i++)
#pragma unroll
            for (int j = 0; j < 4; j++)
                acc[i][j] = __builtin_amdgcn_mfma_f32_16x16x32_bf16(a[i], b[j], acc[i][j], 0, 0, 0);
        __syncthreads();
    }

    // C/D layout: col = lane&15, row = quad*4 + r  [m89/m91]
#pragma unroll
    for (int im = 0; im < FRM; ++im) {
#pragma unroll
        for (int r = 0; r < 4; ++r) {
            const int gm = bm + wm + im * 16 + quad * 4 + r;
            if (EPI == EPI_XP) {
                float s = 0.f;
#pragma unroll
                for (int jn = 0; jn < 4; ++jn) {
                    const int gn = bn + wn + jn * 16 + l15;
                    const float v = acc[im][jn][r] + bias[gn];
                    outb[(size_t)gm * N + gn] = f2b(v);
                    s += v * v;
                }
#pragma unroll
                for (int m = 1; m < 16; m <<= 1) s += __shfl_xor(s, m, 64);
                if (l15 == 0) atomicAdd(&Dacc[gm], s);
            } else if (EPI == EPI_BF) {
#pragma unroll
                for (int jn = 0; jn < 4; ++jn) {
                    const int gn = bn + wn + jn * 16 + l15;
                    outb[(size_t)gm * N + gn] = f2b(acc[im][jn][r]);
                }
            } else if (EPI == EPI_AT) {
                const float dy = Drow[gm];
#pragma unroll
                for (int jn = 0; jn < 4; ++jn) {
                    const int gn = bn + wn + jn * 16 + l15;
                    const float v = 2.f * acc[im][jn][r] / (Dcol[gn] + dy);
                    outb[(size_t)gm * N + gn] = f2b(v);
                }
            } else {  // EPI_RELU
#pragma unroll
                for (int jn = 0; jn < 4; ++jn) {
                    const int gn = bn + wn + jn * 16 + l15;
                    const float v = acc[im][jn][r] + bias[gn];
                    outf[(size_t)gm * N + gn] = fmaxf(v, 0.f);
                }
            }
        }
    }
}

// xp/yp = x@W + b, row norms. grid(4,128), tile 64x128, K=1024.
__global__ __launch_bounds__(256)
void k_proj(const short* __restrict__ A, const short* __restrict__ Bt,
            const float* __restrict__ bias, short* __restrict__ outb,
            float* __restrict__ Dacc)
{
    gemm_core<EPI_XP, 64, 128>(A, 1024, Bt, 1024, 512, 1024,
                               blockIdx.y * 64, blockIdx.x * 128,
                               bias, outb, nullptr, Dacc, nullptr, nullptr);
}

// zT = Wg^T @ xp^T  [512 x 8192] bf16. grid(64,8), tile 64x128, K=512.
__global__ __launch_bounds__(256)
void k_zT(const short* __restrict__ WgT, const short* __restrict__ xpb,
          short* __restrict__ zT)
{
    gemm_core<EPI_BF, 64, 128>(WgT, 512, xpb, 512, 8192, 512,
                               blockIdx.y * 64, blockIdx.x * 128,
                               nullptr, zT, nullptr, nullptr, nullptr, nullptr);
}

// At[j,i]. flat grid 4096; 8x8-block supertile per XCD (R3-proven swizzle).
__global__ __launch_bounds__(256)
void k_aff(const short* __restrict__ ypb, const short* __restrict__ xpb,
           short* __restrict__ At, const float* __restrict__ Dy,
           const float* __restrict__ Dx)
{
    const int flat = blockIdx.x;
    const int x  = flat & 7;
    const int q  = flat >> 3;
    const int st = q >> 6;
    const int w  = q & 63;
    const int s  = x * 8 + st;
    const int bx = (s & 7) * 8 + (w & 7);
    const int by = (s >> 3) * 8 + (w >> 3);
    gemm_core<EPI_AT, 128, 128>(ypb, 512, xpb, 512, 8192, 512,
                                by * 128, bx * 128,
                                nullptr, At, nullptr, nullptr, Dy, Dx);
}

// out = relu(At @ z + bg). flat grid 512, tile 128x64, K=8192.
// 8 bn-blocks of one bm-slice land on one XCD -> At row-slice L2-shared.
__global__ __launch_bounds__(256)
void k_agg(const short* __restrict__ At, const short* __restrict__ zT,
           const float* __restrict__ bg, float* __restrict__ out)
{
    const int flat = blockIdx.x;
    const int xcd = flat & 7;
    const int q   = flat >> 3;
    const int bm  = (xcd * 8 + (q >> 3)) * 128;
    const int bn  = (q & 7) * 64;
    gemm_core<EPI_RELU, 128, 64>(At, 8192, zT, 8192, 512, 8192,
                                 bm, bn,
                                 bg, nullptr, out, nullptr, nullptr, nullptr);
}

// =========================== helpers =======================================
__global__ __launch_bounds__(256)
void k_cvt(const float* __restrict__ in, short* __restrict__ out)
{
    const int i = (blockIdx.x * 256 + threadIdx.x) * 4;
    const float4 v = *(const float4*)&in[i];
    bf16x4 b;
    b[0] = f2b(v.x); b[1] = f2b(v.y); b[2] = f2b(v.z); b[3] = f2b(v.w);
    *(bf16x4*)&out[i] = b;
}

__global__ __launch_bounds__(256)
void transpose_f32_bf16(const float* __restrict__ in, short* __restrict__ out, int R, int C)
{
    __shared__ short t[32][33];
    const int tx = threadIdx.x, ty = threadIdx.y;
    const int bx = blockIdx.x * 32, by = blockIdx.y * 32;
#pragma unroll
    for (int i = 0; i < 32; i += 8)
        t[ty + i][tx] = f2b(in[(size_t)(by + ty + i) * C + bx + tx]);
    __syncthreads();
#pragma unroll
    for (int i = 0; i < 32; i += 8)
        out[(size_t)(bx + ty + i) * R + by + tx] = t[tx][ty + i];
}

extern "C" void kernel_launch(void* const* d_in, const int* in_sizes, int n_in,
                              void* d_out, int out_size, void* d_ws, size_t ws_size,
                              hipStream_t stream)
{
    const float* x  = (const float*)d_in[0];
    const float* y  = (const float*)d_in[1];
    const float* Wx = (const float*)d_in[2];
    const float* bx = (const float*)d_in[3];
    const float* Wy = (const float*)d_in[4];
    const float* by = (const float*)d_in[5];
    const float* Wg = (const float*)d_in[6];
    const float* bg = (const float*)d_in[7];
    float* out = (float*)d_out;                // [8192, 512] f32

    char* p = (char*)d_ws;
    short* At   = (short*)p;                   // [0, 128 MB)
    short* xb   = (short*)p;                   // 16 MB, aliases At (dead by k_aff)
    short* yb   = (short*)(p + (size_t)8192 * 1024 * 2);   // next 16 MB, ditto
    p += (size_t)8192 * 8192 * 2;
    short* xpb  = (short*)p; p += (size_t)8192 * 512 * 2;
    short* ypb  = (short*)p; p += (size_t)8192 * 512 * 2;
    short* zT   = (short*)p; p += (size_t)512 * 8192 * 2;
    short* WxT  = (short*)p; p += (size_t)512 * 1024 * 2;
    short* WyT  = (short*)p; p += (size_t)512 * 1024 * 2;
    short* WgT  = (short*)p; p += (size_t)512 * 512 * 2;
    float* Dx   = (float*)p; p += (size_t)8192 * 4;
    float* Dy   = (float*)p; p += (size_t)8192 * 4;

    hipMemsetAsync(Dx, 0, 2 * 8192 * sizeof(float), stream);  // Dx,Dy contiguous

    dim3 tb(32, 8);
    transpose_f32_bf16<<<dim3(512 / 32, 1024 / 32), tb, 0, stream>>>(Wx, WxT, 1024, 512);
    transpose_f32_bf16<<<dim3(512 / 32, 1024 / 32), tb, 0, stream>>>(Wy, WyT, 1024, 512);
    transpose_f32_bf16<<<dim3(512 / 32, 512 / 32),  tb, 0, stream>>>(Wg, WgT, 512, 512);

    k_cvt<<<8192, 256, 0, stream>>>(x, xb);
    k_cvt<<<8192, 256, 0, stream>>>(y, yb);

    k_proj<<<dim3(4, 128), 256, 0, stream>>>(xb, WxT, bx, xpb, Dx);
    k_proj<<<dim3(4, 128), 256, 0, stream>>>(yb, WyT, by, ypb, Dy);

    k_zT<<<dim3(64, 8), 256, 0, stream>>>(WgT, xpb, zT);

    k_aff<<<4096, 256, 0, stream>>>(ypb, xpb, At, Dy, Dx);

    k_agg<<<512, 256, 0, stream>>>(At, zT, bg, out);
}

// Round 10
// 379.758 us; speedup vs baseline: 1.3978x; 1.0439x over previous
//
#include <hip/hip_runtime.h>
#include <hip/hip_bf16.h>

// BaseQVLayer, R10 (R8-proven core + split-K k_agg, NO LDS-bounce epilogue):
//   xp = x@Wx+bx; yp = y@Wy+by    (k_proj + row-norms)
//   zT = Wg^T @ xp^T [512 x 8192] (k_zT; associativity: out = A^T@(xp@Wg)+bg)
//   At[j,i] = 2*(yp_j.xp_i)/(Dx_i+Dy_j)   (k_aff, 128 MB bf16, R8 scalar epi)
//   p0/p1 = At @ z split-K halves (k_agg, 1024 blocks = 4/CU)
//   out = relu(p0+p1+bg)                  (k_fin)
//
// FAILURE CORRELATION (R6/R7/R9 all hung the container; R8 passed): the one
// feature unique to all failures is the LDS-bounce epilogue unioned with the
// staging buffers inside gemm_core. It is BANNED from this codebase. Split-K
// and k_fin (R9's other deltas) are retained — they are R8-proven primitives.
//
// Workspace 154.6 MB: At [0,128 MB) with xb/yb aliased (dead after k_proj);
// xpb 8 | ypb 8 | zT 8 | WxT 1 | WyT 1 | WgT .5 | Dx,Dy.
// p0/p1 alias xpb/ypb (dead after k_aff).

typedef __attribute__((ext_vector_type(8))) short bf16x8;
typedef __attribute__((ext_vector_type(4))) short bf16x4;
typedef __attribute__((ext_vector_type(4))) float f32x4;

__device__ __forceinline__ short f2b(float f) {
    unsigned int u = __builtin_bit_cast(unsigned int, f);
    unsigned int r = (u + 0x7fffu + ((u >> 16) & 1u)) >> 16;
    return (short)r;
}
__device__ __forceinline__ float b2f(short s) {
    unsigned int u = ((unsigned int)(unsigned short)s) << 16;
    return __builtin_bit_cast(float, u);
}

// async global->LDS, 16 B/lane. LDS dest = wave-uniform base + lane*16.
__device__ __forceinline__ void cp16(const void* g, void* l) {
    __builtin_amdgcn_global_load_lds(
        (const __attribute__((address_space(1))) void*)g,
        (__attribute__((address_space(3))) void*)l, 16, 0, 0);
}

constexpr int EPI_XP = 0;  // +bias, store bf16, atomic row-norm
constexpr int EPI_BF = 1;  // store bf16 (zT, k_agg partials)
constexpr int EPI_AT = 2;  // dice scale, store bf16 (scalar stores, R8-proven)

// C = A @ Bt^T. TM x TN tile, 256 threads (4 waves), BK=32 (R8-proven shape).
// TN=128: waves 2x2, wave-tile (FRM*16)x64. TN=64: waves 4x1, wave-tile 32x64.
template<int EPI, int TM, int TN>
__device__ __forceinline__ void gemm_core(
    const short* __restrict__ A, int lda,
    const short* __restrict__ Bt, int ldb,
    int N, int K, int bm, int bn, int kbase,
    const float* __restrict__ bias,
    short* __restrict__ outb,
    float* __restrict__ Dacc,
    const float* __restrict__ Drow, const float* __restrict__ Dcol)
{
    constexpr int FRM = (TN == 128) ? (TM / 32) : 2;
    __shared__ __align__(16) short As[TM * 32];
    __shared__ __align__(16) short Bs[TN * 32];

    const int tid  = threadIdx.x;
    const int wave = tid >> 6;
    const int lane = tid & 63;
    const int quad = lane >> 4;
    const int l15  = lane & 15;
    const int wn   = (TN == 128) ? (wave & 1) * 64 : 0;
    const int wm   = (TN == 128) ? (wave >> 1) * (FRM * 16) : wave * 32;

    f32x4 acc[FRM][4];
#pragma unroll
    for (int i = 0; i < FRM; i++)
#pragma unroll
        for (int j = 0; j < 4; j++) acc[i][j] = f32x4{0.f, 0.f, 0.f, 0.f};

    for (int k0 = kbase; k0 < kbase + K; k0 += 32) {
#pragma unroll
        for (int s = 0; s < TM / 64; s++) {          // A: TM rows x 4 granules
            const int seg = tid + 256 * s;
            const int row = seg >> 2, c8 = seg & 3;
            cp16(&A[(size_t)(bm + row) * lda + k0 + c8 * 8], &As[seg * 8]);
        }
#pragma unroll
        for (int s = 0; s < TN / 64; s++) {          // B: TN rows x 4 granules
            const int seg = tid + 256 * s;
            const int row = seg >> 2, c8 = seg & 3;
            cp16(&Bt[(size_t)(bn + row) * ldb + k0 + c8 * 8], &Bs[seg * 8]);
        }
        __syncthreads();

        bf16x8 a[FRM], b[4];
#pragma unroll
        for (int i = 0; i < FRM; i++)
            a[i] = *(const bf16x8*)&As[(wm + i * 16 + l15) * 32 + quad * 8];
#pragma unroll
        for (int j = 0; j < 4; j++)
            b[j] = *(const bf16x8*)&Bs[(wn + j * 16 + l15) * 32 + quad * 8];
#pragma unroll
        for (int i = 0; i < FRM; i++)
#pragma unroll
            for (int j = 0; j < 4; j++)
                acc[i][j] = __builtin_amdgcn_mfma_f32_16x16x32_bf16(a[i], b[j], acc[i][j], 0, 0, 0);
        __syncthreads();
    }

    // C/D layout: col = lane&15, row = quad*4 + r  [m89/m91]
#pragma unroll
    for (int im = 0; im < FRM; ++im) {
#pragma unroll
        for (int r = 0; r < 4; ++r) {
            const int gm = bm + wm + im * 16 + quad * 4 + r;
            if (EPI == EPI_XP) {
                float s = 0.f;
#pragma unroll
                for (int jn = 0; jn < 4; ++jn) {
                    const int gn = bn + wn + jn * 16 + l15;
                    const float v = acc[im][jn][r] + bias[gn];
                    outb[(size_t)gm * N + gn] = f2b(v);
                    s += v * v;
                }
#pragma unroll
                for (int m = 1; m < 16; m <<= 1) s += __shfl_xor(s, m, 64);
                if (l15 == 0) atomicAdd(&Dacc[gm], s);
            } else if (EPI == EPI_BF) {
#pragma unroll
                for (int jn = 0; jn < 4; ++jn) {
                    const int gn = bn + wn + jn * 16 + l15;
                    outb[(size_t)gm * N + gn] = f2b(acc[im][jn][r]);
                }
            } else {  // EPI_AT
                const float dy = Drow[gm];
#pragma unroll
                for (int jn = 0; jn < 4; ++jn) {
                    const int gn = bn + wn + jn * 16 + l15;
                    const float v = 2.f * acc[im][jn][r] / (Dcol[gn] + dy);
                    outb[(size_t)gm * N + gn] = f2b(v);
                }
            }
        }
    }
}

// xp/yp = x@W + b, row norms. grid(4,128), tile 64x128, K=1024.
__global__ __launch_bounds__(256)
void k_proj(const short* __restrict__ A, const short* __restrict__ Bt,
            const float* __restrict__ bias, short* __restrict__ outb,
            float* __restrict__ Dacc)
{
    gemm_core<EPI_XP, 64, 128>(A, 1024, Bt, 1024, 512, 1024,
                               blockIdx.y * 64, blockIdx.x * 128, 0,
                               bias, outb, Dacc, nullptr, nullptr);
}

// zT = Wg^T @ xp^T  [512 x 8192] bf16. grid(64,8), tile 64x128, K=512.
__global__ __launch_bounds__(256)
void k_zT(const short* __restrict__ WgT, const short* __restrict__ xpb,
          short* __restrict__ zT)
{
    gemm_core<EPI_BF, 64, 128>(WgT, 512, xpb, 512, 8192, 512,
                               blockIdx.y * 64, blockIdx.x * 128, 0,
                               nullptr, zT, nullptr, nullptr, nullptr);
}

// At[j,i]. flat grid 4096; 8x8-block supertile per XCD (R3/R8-proven).
__global__ __launch_bounds__(256)
void k_aff(const short* __restrict__ ypb, const short* __restrict__ xpb,
           short* __restrict__ At, const float* __restrict__ Dy,
           const float* __restrict__ Dx)
{
    const int flat = blockIdx.x;
    const int x  = flat & 7;
    const int q  = flat >> 3;
    const int st = q >> 6;
    const int w  = q & 63;
    const int s  = x * 8 + st;
    const int bx = (s & 7) * 8 + (w & 7);
    const int by = (s >> 3) * 8 + (w >> 3);
    gemm_core<EPI_AT, 128, 128>(ypb, 512, xpb, 512, 8192, 512,
                                by * 128, bx * 128, 0,
                                nullptr, At, nullptr, Dy, Dx);
}

// Split-K At@z partials. flat grid 1024 (4 blocks/CU). Group = (bm, z): its
// 8 bn-blocks land on one XCD so the 1 MB At slice is L2-shared.
__global__ __launch_bounds__(256)
void k_agg(const short* __restrict__ At, const short* __restrict__ zT,
           short* __restrict__ p0, short* __restrict__ p1)
{
    const int flat = blockIdx.x;
    const int xcd = flat & 7;
    const int q   = flat >> 3;            // 0..127 within XCD
    const int g   = xcd * 16 + (q >> 3);  // group 0..127
    const int bm  = (g >> 1) * 128;
    const int z   = g & 1;
    const int bn  = (q & 7) * 64;
    short* outb = z ? p1 : p0;
    gemm_core<EPI_BF, 128, 64>(At, 8192, zT, 8192, 512, 4096,
                               bm, bn, z * 4096,
                               nullptr, outb, nullptr, nullptr, nullptr);
}

// out = relu(p0 + p1 + bg). 8 elems/thread, 2048 blocks.
__global__ __launch_bounds__(256)
void k_fin(const short* __restrict__ p0, const short* __restrict__ p1,
           const float* __restrict__ bg, float* __restrict__ out)
{
    const int idx = (blockIdx.x * 256 + threadIdx.x) * 8;
    const int col = idx & 511;
    const bf16x8 a = *(const bf16x8*)&p0[idx];
    const bf16x8 b = *(const bf16x8*)&p1[idx];
    const f32x4 g0 = *(const f32x4*)&bg[col];
    const f32x4 g1 = *(const f32x4*)&bg[col + 4];
    f32x4 o0, o1;
#pragma unroll
    for (int e = 0; e < 4; ++e) {
        o0[e] = fmaxf(b2f(a[e]) + b2f(b[e]) + g0[e], 0.f);
        o1[e] = fmaxf(b2f(a[e + 4]) + b2f(b[e + 4]) + g1[e], 0.f);
    }
    *(f32x4*)&out[idx]     = o0;
    *(f32x4*)&out[idx + 4] = o1;
}

// =========================== helpers =======================================
__global__ __launch_bounds__(256)
void k_cvt(const float* __restrict__ in, short* __restrict__ out)
{
    const int i = (blockIdx.x * 256 + threadIdx.x) * 4;
    const float4 v = *(const float4*)&in[i];
    bf16x4 b;
    b[0] = f2b(v.x); b[1] = f2b(v.y); b[2] = f2b(v.z); b[3] = f2b(v.w);
    *(bf16x4*)&out[i] = b;
}

__global__ __launch_bounds__(256)
void transpose_f32_bf16(const float* __restrict__ in, short* __restrict__ out, int R, int C)
{
    __shared__ short t[32][33];
    const int tx = threadIdx.x, ty = threadIdx.y;
    const int bx = blockIdx.x * 32, by = blockIdx.y * 32;
#pragma unroll
    for (int i = 0; i < 32; i += 8)
        t[ty + i][tx] = f2b(in[(size_t)(by + ty + i) * C + bx + tx]);
    __syncthreads();
#pragma unroll
    for (int i = 0; i < 32; i += 8)
        out[(size_t)(bx + ty + i) * R + by + tx] = t[tx][ty + i];
}

extern "C" void kernel_launch(void* const* d_in, const int* in_sizes, int n_in,
                              void* d_out, int out_size, void* d_ws, size_t ws_size,
                              hipStream_t stream)
{
    const float* x  = (const float*)d_in[0];
    const float* y  = (const float*)d_in[1];
    const float* Wx = (const float*)d_in[2];
    const float* bx = (const float*)d_in[3];
    const float* Wy = (const float*)d_in[4];
    const float* by = (const float*)d_in[5];
    const float* Wg = (const float*)d_in[6];
    const float* bg = (const float*)d_in[7];
    float* out = (float*)d_out;                // [8192, 512] f32

    char* p = (char*)d_ws;
    short* At   = (short*)p;                   // [0, 128 MB)
    short* xb   = (short*)p;                   // 16 MB, aliases At (dead by k_aff)
    short* yb   = (short*)(p + (size_t)8192 * 1024 * 2);   // next 16 MB, ditto
    p += (size_t)8192 * 8192 * 2;
    short* xpb  = (short*)p; p += (size_t)8192 * 512 * 2;
    short* ypb  = (short*)p; p += (size_t)8192 * 512 * 2;
    short* zT   = (short*)p; p += (size_t)512 * 8192 * 2;
    short* WxT  = (short*)p; p += (size_t)512 * 1024 * 2;
    short* WyT  = (short*)p; p += (size_t)512 * 1024 * 2;
    short* WgT  = (short*)p; p += (size_t)512 * 512 * 2;
    float* Dx   = (float*)p; p += (size_t)8192 * 4;
    float* Dy   = (float*)p; p += (size_t)8192 * 4;
    // split-K partials alias xpb/ypb (dead after k_aff)
    short* p0 = xpb;
    short* p1 = ypb;

    hipMemsetAsync(Dx, 0, 2 * 8192 * sizeof(float), stream);  // Dx,Dy contiguous

    dim3 tb(32, 8);
    transpose_f32_bf16<<<dim3(512 / 32, 1024 / 32), tb, 0, stream>>>(Wx, WxT, 1024, 512);
    transpose_f32_bf16<<<dim3(512 / 32, 1024 / 32), tb, 0, stream>>>(Wy, WyT, 1024, 512);
    transpose_f32_bf16<<<dim3(512 / 32, 512 / 32),  tb, 0, stream>>>(Wg, WgT, 512, 512);

    k_cvt<<<8192, 256, 0, stream>>>(x, xb);
    k_cvt<<<8192, 256, 0, stream>>>(y, yb);

    k_proj<<<dim3(4, 128), 256, 0, stream>>>(xb, WxT, bx, xpb, Dx);
    k_proj<<<dim3(4, 128), 256, 0, stream>>>(yb, WyT, by, ypb, Dy);

    k_zT<<<dim3(64, 8), 256, 0, stream>>>(WgT, xpb, zT);

    k_aff<<<4096, 256, 0, stream>>>(ypb, xpb, At, Dy, Dx);

    k_agg<<<1024, 256, 0, stream>>>(At, zT, p0, p1);

    k_fin<<<2048, 256, 0, stream>>>(p0, p1, bg, out);
}